// Round 4
// baseline (120.524 us; speedup 1.0000x reference)
//
#include <hip/hip_runtime.h>
#include <hip/hip_cooperative_groups.h>
#include <cfloat>

namespace cg = cooperative_groups;

#define TPB 256
#define BKT 32768                 // buckets per side (2048 per unit over [-8,8))
#define SLOTS 16                  // floats per bucket = one 64B line
#define OVCAP 4096                // overflow capacity per side (expected 0 used)
#define RLO -8.0f
#define RSCALE (BKT / 16.0f)      // exact power of two
#define ALPHA 0.5f

// ---- workspace layout (uint words) -------------------------------------
// zeroed in-kernel (phase Z): cnt | bm1 | bm2 | overflow counters
#define CNT_OFF   0                         // cnt[2*BKT]
#define BM1_OFF   (2 * BKT)                 // 2*1024 words (built by atomicOr)
#define BM2_OFF   (BM1_OFF + 2048)          // 2*32 words
#define OVC_OFF   (BM2_OFF + 64)            // 2 words
#define ZERO_WORDS (OVC_OFF + 2)
// not zeroed (reads gated by cnt / ovc):
#define SLOTS_OFF (((ZERO_WORDS) + 63) & ~63)   // floats, 2*BKT*SLOTS (64B-aligned)
#define OVF_OFF   (SLOTS_OFF + 2 * BKT * SLOTS) // floats, 2*OVCAP

// Monotone non-decreasing (fl(v+8) monotone, *2048 exact pow2, trunc+clamp
// monotone) => bucket(u) < bucket(w) implies u < w.
__device__ __forceinline__ int bucket_of(float v) {
    int b = (int)((v - RLO) * RSCALE);
    return min(max(b, 0), BKT - 1);
}

// Previous/next nonempty bucket via 2-level bitmap (bounded, no bucket walk).
__device__ __forceinline__ int prev_ne(const unsigned* __restrict__ bm1,
                                       const unsigned* __restrict__ bm2, int b) {
    if (b == 0) return -1;
    const int p = b - 1;
    unsigned w = bm1[p >> 5] & (~0u >> (31 - (p & 31)));
    if (w) return (p & ~31) | (31 - __clz(w));
    const int W = (p >> 5) - 1;
    if (W < 0) return -1;
    int j = W >> 5;
    unsigned w2 = bm2[j] & (~0u >> (31 - (W & 31)));
    while (!w2 && --j >= 0) w2 = bm2[j];
    if (!w2) return -1;
    const int Wp = (j << 5) | (31 - __clz(w2));
    return (Wp << 5) | (31 - __clz(bm1[Wp]));
}
__device__ __forceinline__ int next_ne(const unsigned* __restrict__ bm1,
                                       const unsigned* __restrict__ bm2, int b) {
    if (b >= BKT - 1) return -1;
    const int p = b + 1;
    unsigned w = bm1[p >> 5] & (~0u << (p & 31));
    if (w) return (p & ~31) | (__ffs(w) - 1);
    const int W = (p >> 5) + 1;
    if (W > 1023) return -1;
    int j = W >> 5;
    unsigned w2 = bm2[j] & (~0u << (W & 31));
    while (!w2 && ++j < 32) w2 = bm2[j];
    if (!w2) return -1;
    const int Wp = (j << 5) | (__ffs(w2) - 1);
    return (Wp << 5) | (__ffs(bm1[Wp]) - 1);
}

// Min |v - e| over one bucket's slot line: 4 independent uint4 loads,
// count-masked in registers. Slots beyond cnt are garbage but excluded.
__device__ __forceinline__ float scan_bucket(const unsigned* __restrict__ cnt,
                                             const float* __restrict__ slots,
                                             int side, int b, float v, float best) {
    const unsigned c = min(cnt[b], (unsigned)SLOTS);
    const float4* sl4 = (const float4*)(slots + ((size_t)(side * BKT + b)) * SLOTS);
    float e[SLOTS];
    *(float4*)(e + 0)  = sl4[0];
    *(float4*)(e + 4)  = sl4[1];
    *(float4*)(e + 8)  = sl4[2];
    *(float4*)(e + 12) = sl4[3];
#pragma unroll
    for (int j = 0; j < SLOTS; ++j) {
        const float d = fabsf(v - e[j]);
        best = ((unsigned)j < c) ? fminf(best, d) : best;
    }
    return best;
}

// ---- single cooperative kernel: zero -> build(+bitmap) -> query -> final ----
// Exactness: candidates = own bucket + nearest nonempty bucket below + nearest
// nonempty bucket above + full overflow list. The value-order predecessor and
// successor of v are always in this set (bucket map monotone), every candidate
// is a real element, f32 |v-y| rounding is monotone in true distance => min
// over candidates == min over all pairs. Reduction order is fixed => bitwise
// deterministic result (absmax 0 in R1-R3 with identical arithmetic).
__global__ __launch_bounds__(TPB) void
chamfer_fused(const float* __restrict__ x, const float* __restrict__ y,
              int n, int m, unsigned* __restrict__ ws,
              double* __restrict__ bsums, float* __restrict__ out) {
    cg::grid_group grid = cg::this_grid();
    const int tid = blockIdx.x * TPB + (int)threadIdx.x;
    const int gsz = (int)gridDim.x * TPB;
    const int total = n + m;

    // ---- phase Z: zero metadata (264 KB across the grid) ----
    for (int w = tid; w < ZERO_WORDS; w += gsz) ws[w] = 0u;
    grid.sync();

    // ---- phase B: histogram + slot scatter + gated occupancy bits ----
    // cnt atomicAdd: ~lambda=3.2 ops/bucket, contention-free.
    // bm1 atomicOr only for pos==0: <=32 ops/word. bm2 atomicOr only when the
    // bm1 word transitions 0->nonzero (old==0): <=32 ops/word. (R2 lesson:
    // ungated bm2 had ~3100 serialized ops on the central word = 90+ us.)
    for (int i = tid; i < total; i += gsz) {
        const bool isx = i < n;
        const int side = isx ? 0 : 1;
        const float v = isx ? x[i] : y[i - n];
        const int b = bucket_of(v);
        const unsigned pos = atomicAdd(ws + CNT_OFF + side * BKT + b, 1u);
        if (pos < SLOTS) {
            ((float*)(ws + SLOTS_OFF))[((size_t)(side * BKT + b)) * SLOTS + pos] = v;
        } else {
            const unsigned o = atomicAdd(ws + OVC_OFF + side, 1u);
            if (o < OVCAP) ((float*)(ws + OVF_OFF))[side * OVCAP + o] = v;
        }
        if (pos == 0) {
            const int W = b >> 5;
            const unsigned old =
                atomicOr(ws + BM1_OFF + side * 1024 + W, 1u << (b & 31));
            if (old == 0)
                atomicOr(ws + BM2_OFF + side * 32 + (W >> 5), 1u << (W & 31));
        }
    }
    grid.sync();

    // ---- phase Q: per-query NN + deterministic block reduction ----
    {
        const int q = tid;
        double sx = 0.0, sy = 0.0;
        if (q < total) {
            const bool isx = q < n;
            const float v = isx ? x[q] : y[q - n];
            const int side = isx ? 1 : 0;        // search the OTHER side
            const unsigned* cnt = ws + CNT_OFF + side * BKT;
            const unsigned* bm1 = ws + BM1_OFF + side * 1024;
            const unsigned* bm2 = ws + BM2_OFF + side * 32;
            const float* slots = (const float*)(ws + SLOTS_OFF);
            const int b = bucket_of(v);

            float best = scan_bucket(cnt, slots, side, b, v, FLT_MAX);
            const int bp = prev_ne(bm1, bm2, b);
            if (bp >= 0) best = scan_bucket(cnt, slots, side, bp, v, best);
            const int bn = next_ne(bm1, bm2, b);
            if (bn >= 0) best = scan_bucket(cnt, slots, side, bn, v, best);

            const unsigned oc = min(ws[OVC_OFF + side], (unsigned)OVCAP);
            const float* ovf = (const float*)(ws + OVF_OFF) + side * OVCAP;
            for (unsigned k = 0; k < oc; ++k)
                best = fminf(best, fabsf(v - ovf[k]));

            if (isx) sx = (double)best; else sy = (double)best;
        }
        for (int off = 32; off > 0; off >>= 1) {
            sx += __shfl_down(sx, off);
            sy += __shfl_down(sy, off);
        }
        __shared__ double wsx[TPB / 64], wsy[TPB / 64];
        const int w = threadIdx.x >> 6;
        if ((threadIdx.x & 63) == 0) { wsx[w] = sx; wsy[w] = sy; }
        __syncthreads();
        if (threadIdx.x == 0) {
            double tx = 0.0, ty = 0.0;
#pragma unroll
            for (int i = 0; i < TPB / 64; ++i) { tx += wsx[i]; ty += wsy[i]; }
            bsums[2 * blockIdx.x] = tx;
            bsums[2 * blockIdx.x + 1] = ty;
        }
    }
    grid.sync();

    // ---- phase F: block 0 folds per-block sums -> scalar loss ----
    if (blockIdx.x == 0) {
        const int nb = (int)gridDim.x;
        double sx = 0.0, sy = 0.0;
        for (int i = (int)threadIdx.x; i < nb; i += TPB) {
            sx += bsums[2 * i];
            sy += bsums[2 * i + 1];
        }
        for (int off = 32; off > 0; off >>= 1) {
            sx += __shfl_down(sx, off);
            sy += __shfl_down(sy, off);
        }
        __shared__ double lsx[TPB / 64], lsy[TPB / 64];
        const int wave = threadIdx.x >> 6;
        if ((threadIdx.x & 63) == 0) { lsx[wave] = sx; lsy[wave] = sy; }
        __syncthreads();
        if (threadIdx.x == 0) {
            double tx = 0.0, ty = 0.0;
#pragma unroll
            for (int w = 0; w < TPB / 64; ++w) { tx += lsx[w]; ty += lsy[w]; }
            const double a = (double)ALPHA;
            out[0] = (float)(a * tx / (double)n + (1.0 - a) * ty / (double)m);
        }
    }
}

extern "C" void kernel_launch(void* const* d_in, const int* in_sizes, int n_in,
                              void* d_out, int out_size, void* d_ws, size_t ws_size,
                              hipStream_t stream) {
    const float* x = (const float*)d_in[0];
    const float* y = (const float*)d_in[1];
    int n = in_sizes[0];
    int m = in_sizes[1];
    float* out = (float*)d_out;
    const int total = n + m;

    unsigned* ws = (unsigned*)d_ws;
    const size_t meta_bytes = (size_t)(OVF_OFF + 2 * OVCAP) * sizeof(unsigned);
    const size_t meta_al = (meta_bytes + 255) & ~(size_t)255;
    double* bsums = (double*)((char*)d_ws + meta_al);

    // 128 blocks for 32768 points: 512 waves, trivially co-resident on 256 CUs.
    int nb = (total + TPB - 1) / TPB;
    if (nb > 2048) nb = 2048;      // co-residency cap (8 blocks/CU); loops stride

    void* args[] = {(void*)&x, (void*)&y, (void*)&n, (void*)&m,
                    (void*)&ws, (void*)&bsums, (void*)&out};
    hipLaunchCooperativeKernel((const void*)chamfer_fused, dim3(nb), dim3(TPB),
                               args, 0, stream);
}

// Round 5
// 73.783 us; speedup vs baseline: 1.6335x; 1.6335x over previous
//
#include <hip/hip_runtime.h>
#include <cfloat>

#define TPB 256
#define BKT 32768                 // buckets per side (2048 per unit over [-8,8))
#define SLOTS 16                  // floats per bucket = one 64B line
#define OVCAP 4096                // overflow capacity per side (expected 0 used)
#define RLO -8.0f
#define RSCALE (BKT / 16.0f)      // exact power of two
#define ALPHA 0.5f

// ---- workspace layout (uint words) -------------------------------------
// zeroed by ONE hipMemsetAsync: cnt | bm1 | bm2 | ovc | done
#define CNT_OFF   0                         // cnt[2*BKT]
#define BM1_OFF   (2 * BKT)                 // 2*1024 words (gated atomicOr)
#define BM2_OFF   (BM1_OFF + 2048)          // 2*32 words (gated atomicOr)
#define OVC_OFF   (BM2_OFF + 64)            // 2 words
#define DONE_OFF  (OVC_OFF + 2)             // 1 word (last-block counter)
#define ZERO_WORDS (DONE_OFF + 1)
// not zeroed (reads gated by cnt / ovc):
#define SLOTS_OFF (((ZERO_WORDS) + 63) & ~63)   // floats, 2*BKT*SLOTS (64B-aligned)
#define OVF_OFF   (SLOTS_OFF + 2 * BKT * SLOTS) // floats, 2*OVCAP

// Monotone non-decreasing (fl(v+8) monotone, *2048 exact pow2, trunc+clamp
// monotone) => bucket(u) < bucket(w) implies u < w.
__device__ __forceinline__ int bucket_of(float v) {
    int b = (int)((v - RLO) * RSCALE);
    return min(max(b, 0), BKT - 1);
}

// ---- build: histogram + slot scatter + GATED occupancy bits -------------
// cnt atomicAdd: ~4 ops/bucket, contention-free. bm1 atomicOr only when
// pos==0 (<=32 ops/word); bm2 atomicOr only when bm1 word went 0->nonzero
// (<=32 ops/word). R2 lesson: the UNGATED bm2 version serialized ~3100
// atomicOr on the central word = 90+ us. R4 validated this gated form.
__global__ __launch_bounds__(TPB) void
chamfer_build(const float* __restrict__ x, const float* __restrict__ y,
              int n, int m, unsigned* __restrict__ ws) {
    const int i = blockIdx.x * TPB + threadIdx.x;
    if (i >= n + m) return;
    const bool isx = i < n;
    const int side = isx ? 0 : 1;
    const float v = isx ? x[i] : y[i - n];
    const int b = bucket_of(v);
    const unsigned pos = atomicAdd(ws + CNT_OFF + side * BKT + b, 1u);
    if (pos < SLOTS) {
        ((float*)(ws + SLOTS_OFF))[((size_t)(side * BKT + b)) * SLOTS + pos] = v;
    } else {
        const unsigned o = atomicAdd(ws + OVC_OFF + side, 1u);
        if (o < OVCAP) ((float*)(ws + OVF_OFF))[side * OVCAP + o] = v;
    }
    if (pos == 0) {
        const int W = b >> 5;
        const unsigned old = atomicOr(ws + BM1_OFF + side * 1024 + W, 1u << (b & 31));
        if (old == 0)
            atomicOr(ws + BM2_OFF + side * 32 + (W >> 5), 1u << (W & 31));
    }
}

// Previous/next nonempty bucket via 2-level bitmap (bounded, no bucket walk).
__device__ __forceinline__ int prev_ne(const unsigned* __restrict__ bm1,
                                       const unsigned* __restrict__ bm2, int b) {
    if (b == 0) return -1;
    const int p = b - 1;
    unsigned w = bm1[p >> 5] & (~0u >> (31 - (p & 31)));
    if (w) return (p & ~31) | (31 - __clz(w));
    const int W = (p >> 5) - 1;
    if (W < 0) return -1;
    int j = W >> 5;
    unsigned w2 = bm2[j] & (~0u >> (31 - (W & 31)));
    while (!w2 && --j >= 0) w2 = bm2[j];
    if (!w2) return -1;
    const int Wp = (j << 5) | (31 - __clz(w2));
    return (Wp << 5) | (31 - __clz(bm1[Wp]));
}
__device__ __forceinline__ int next_ne(const unsigned* __restrict__ bm1,
                                       const unsigned* __restrict__ bm2, int b) {
    if (b >= BKT - 1) return -1;
    const int p = b + 1;
    unsigned w = bm1[p >> 5] & (~0u << (p & 31));
    if (w) return (p & ~31) | (__ffs(w) - 1);
    const int W = (p >> 5) + 1;
    if (W > 1023) return -1;
    int j = W >> 5;
    unsigned w2 = bm2[j] & (~0u << (W & 31));
    while (!w2 && ++j < 32) w2 = bm2[j];
    if (!w2) return -1;
    const int Wp = (j << 5) | (__ffs(w2) - 1);
    return (Wp << 5) | (__ffs(bm1[Wp]) - 1);
}

// Min |v - e| over one bucket's slot line: 4 independent uint4 loads,
// count-masked in registers. Slots beyond cnt are garbage but excluded.
__device__ __forceinline__ float scan_bucket(const unsigned* __restrict__ cnt,
                                             const float* __restrict__ slots,
                                             int side, int b, float v, float best) {
    const unsigned c = min(cnt[b], (unsigned)SLOTS);
    const float4* sl4 = (const float4*)(slots + ((size_t)(side * BKT + b)) * SLOTS);
    float e[SLOTS];
    *(float4*)(e + 0)  = sl4[0];
    *(float4*)(e + 4)  = sl4[1];
    *(float4*)(e + 8)  = sl4[2];
    *(float4*)(e + 12) = sl4[3];
#pragma unroll
    for (int j = 0; j < SLOTS; ++j) {
        const float d = fabsf(v - e[j]);
        best = ((unsigned)j < c) ? fminf(best, d) : best;
    }
    return best;
}

// ---- query + fused final: per-query NN, per-block deterministic partial,
// last finishing block folds all partials (identical order to the old
// chamfer_final => bitwise-identical result, absmax 0).
// Exactness: candidates = own bucket + nearest nonempty bucket below +
// nearest nonempty bucket above + full overflow list. The value-order
// predecessor/successor of v are always in this set (bucket map monotone),
// every candidate is a real element, f32 |v-y| rounding is monotone in true
// distance => min over candidates == min over all pairs.
__global__ __launch_bounds__(TPB) void
chamfer_query(const float* __restrict__ x, const float* __restrict__ y,
              int n, int m, unsigned* __restrict__ ws,
              double* __restrict__ bsums, float* __restrict__ out) {
    const int q = blockIdx.x * TPB + threadIdx.x;
    const int total = n + m;
    double sx = 0.0, sy = 0.0;
    if (q < total) {
        const bool isx = q < n;
        const float v = isx ? x[q] : y[q - n];
        const int side = isx ? 1 : 0;            // search the OTHER side
        const unsigned* cnt = ws + CNT_OFF + side * BKT;
        const unsigned* bm1 = ws + BM1_OFF + side * 1024;
        const unsigned* bm2 = ws + BM2_OFF + side * 32;
        const float* slots = (const float*)(ws + SLOTS_OFF);
        const int b = bucket_of(v);

        float best = scan_bucket(cnt, slots, side, b, v, FLT_MAX);
        const int bp = prev_ne(bm1, bm2, b);
        if (bp >= 0) best = scan_bucket(cnt, slots, side, bp, v, best);
        const int bn = next_ne(bm1, bm2, b);
        if (bn >= 0) best = scan_bucket(cnt, slots, side, bn, v, best);

        const unsigned oc = min(ws[OVC_OFF + side], (unsigned)OVCAP);
        const float* ovf = (const float*)(ws + OVF_OFF) + side * OVCAP;
        for (unsigned k = 0; k < oc; ++k)
            best = fminf(best, fabsf(v - ovf[k]));

        if (isx) sx = (double)best; else sy = (double)best;
    }
    for (int off = 32; off > 0; off >>= 1) {
        sx += __shfl_down(sx, off);
        sy += __shfl_down(sy, off);
    }
    __shared__ double wsx[TPB / 64], wsy[TPB / 64];
    const int w = threadIdx.x >> 6;
    if ((threadIdx.x & 63) == 0) { wsx[w] = sx; wsy[w] = sy; }
    __syncthreads();

    __shared__ bool s_last;
    if (threadIdx.x == 0) {
        double tx = 0.0, ty = 0.0;
#pragma unroll
        for (int i = 0; i < TPB / 64; ++i) { tx += wsx[i]; ty += wsy[i]; }
        bsums[2 * blockIdx.x] = tx;
        bsums[2 * blockIdx.x + 1] = ty;
        __threadfence();                          // release partials (device scope)
        const unsigned old = atomicAdd(ws + DONE_OFF, 1u);
        s_last = (old == gridDim.x - 1);
    }
    __syncthreads();
    if (!s_last) return;

    // last block: acquire + fold partials in the SAME order as before
    __threadfence();
    const int nb = (int)gridDim.x;
    double fx = 0.0, fy = 0.0;
    for (int i = (int)threadIdx.x; i < nb; i += TPB) {
        fx += bsums[2 * i];
        fy += bsums[2 * i + 1];
    }
    for (int off = 32; off > 0; off >>= 1) {
        fx += __shfl_down(fx, off);
        fy += __shfl_down(fy, off);
    }
    __shared__ double lsx[TPB / 64], lsy[TPB / 64];
    const int wave = threadIdx.x >> 6;
    if ((threadIdx.x & 63) == 0) { lsx[wave] = fx; lsy[wave] = fy; }
    __syncthreads();
    if (threadIdx.x == 0) {
        double tx = 0.0, ty = 0.0;
#pragma unroll
        for (int w2 = 0; w2 < TPB / 64; ++w2) { tx += lsx[w2]; ty += lsy[w2]; }
        const double a = (double)ALPHA;
        out[0] = (float)(a * tx / (double)n + (1.0 - a) * ty / (double)m);
    }
}

extern "C" void kernel_launch(void* const* d_in, const int* in_sizes, int n_in,
                              void* d_out, int out_size, void* d_ws, size_t ws_size,
                              hipStream_t stream) {
    const float* x = (const float*)d_in[0];
    const float* y = (const float*)d_in[1];
    const int n = in_sizes[0];
    const int m = in_sizes[1];
    float* out = (float*)d_out;
    const int total = n + m;

    unsigned* ws = (unsigned*)d_ws;
    const size_t meta_bytes = (size_t)(OVF_OFF + 2 * OVCAP) * sizeof(unsigned);
    const size_t meta_al = (meta_bytes + 255) & ~(size_t)255;
    double* bsums = (double*)((char*)d_ws + meta_al);

    const int nb = (total + TPB - 1) / TPB;   // 128 blocks

    hipMemsetAsync(ws, 0, (size_t)ZERO_WORDS * sizeof(unsigned), stream);
    chamfer_build<<<nb, TPB, 0, stream>>>(x, y, n, m, ws);
    chamfer_query<<<nb, TPB, 0, stream>>>(x, y, n, m, ws, bsums, out);
}